// Round 3
// baseline (315.970 us; speedup 1.0000x reference)
//
#include <hip/hip_runtime.h>
#include <stdint.h>

// AttentionGate fused kernel, MI355X gfx950. Inputs confirmed fp32 (R2).
//
// Prepass: convert Wx, Wg fp32 -> bf16 into d_ws (256 KiB).
// Main kernel, per block: 64 contiguous pixels x 256 output channels.
//   K-loop (8 x BK=32), software-prefetched: stage x/g tiles (fp32->bf16
//   micro-transpose) + bf16 W chunks in LDS, 64 MFMA 16x16x32_bf16 per wave
//   pair-iter, fp32 accumulate. Next iter's global loads issued before MFMA
//   phase so latency hides behind compute + barrier.
//   Epilogue: bias+relu in regs; LN + psi-dot fused to 3 per-pixel scalar
//   reductions (s, ss, t) -> sigmoid -> out = psi * x (x re-read, L3-warm).

typedef __bf16 bf16x8 __attribute__((ext_vector_type(8)));
typedef float f32x4 __attribute__((ext_vector_type(4)));

#define STR 40            // LDS row stride in shorts: 32 k + 8 pad (80 B = 5*16 B)
#define LN_EPS 1e-5f

__device__ __forceinline__ uint16_t f2b(float f) {
    union { float f; uint32_t i; } v; v.f = f;
    uint32_t x = v.i;
    return (uint16_t)((x + 0x7FFFu + ((x >> 16) & 1u)) >> 16);  // RNE
}

struct EpiShared {
    float red[3][4][64];   // s, ss, t partials: [value][wave][pixel]
    float psi[64];
    float cpart[8];        // per-wave partials: sumA (0..3), sumB (4..7)
};

union ALds {
    struct { uint16_t Ax[64 * STR]; uint16_t Ag[64 * STR]; } a;  // 10 KiB
    EpiShared e;
};

// ---- prepass: W fp32 -> bf16 (both matrices, 16384 float4 each) ----
__global__ void wconv_kernel(const float4* __restrict__ Wx, const float4* __restrict__ Wg,
                             uint2* __restrict__ ox, uint2* __restrict__ og) {
    const int i = blockIdx.x * 256 + threadIdx.x;   // 64 blocks x 256 = 16384
    const float4 a = Wx[i];
    const float4 b = Wg[i];
    uint2 pa, pb;
    pa.x = (uint32_t)f2b(a.x) | ((uint32_t)f2b(a.y) << 16);
    pa.y = (uint32_t)f2b(a.z) | ((uint32_t)f2b(a.w) << 16);
    pb.x = (uint32_t)f2b(b.x) | ((uint32_t)f2b(b.y) << 16);
    pb.y = (uint32_t)f2b(b.z) | ((uint32_t)f2b(b.w) << 16);
    ox[i] = pa;
    og[i] = pb;
}

__global__ __launch_bounds__(256, 3) void attgate_kernel(
    const float* __restrict__ x,
    const float* __restrict__ g,
    const uint16_t* __restrict__ Wxb,   // bf16, [256][256] k-contiguous
    const uint16_t* __restrict__ Wgb,
    const float* __restrict__ Wpsi,
    const float* __restrict__ gamma,
    const float* __restrict__ beta,
    const float* __restrict__ bxg,
    const float* __restrict__ bpsi,
    float* __restrict__ out)
{
    __shared__ __align__(16) uint16_t WxS[256 * STR];   // 20 KiB
    __shared__ __align__(16) uint16_t WgS[256 * STR];   // 20 KiB
    __shared__ __align__(16) ALds u;                    // 10 KiB

    const int t    = threadIdx.x;
    const int lane = t & 63;
    const int wv   = t >> 6;        // wave 0..3 -> output-channel slice
    const int ln   = lane & 15;     // tile row/col index
    const int q    = lane >> 4;     // quad 0..3

    const int gp0  = blockIdx.x * 64;            // global pixel base
    const int b    = gp0 >> 12;                  // batch (4096 px per image)
    const int pix0 = gp0 & 4095;
    const size_t xbase = (size_t)b * (256 * 4096) + pix0;  // + c*4096 + p

    f32x4 acc[4][4];
    #pragma unroll
    for (int i = 0; i < 4; ++i)
        #pragma unroll
        for (int j = 0; j < 4; ++j)
            acc[i][j] = (f32x4){0.f, 0.f, 0.f, 0.f};

    // ---- precomputed staging offsets (iter-invariant) ----
    // A: half-block each for x and g; thread covers 4 channels x 4 pixels.
    const int at  = t & 127;
    const int apg = at & 15;        // pixel group (4 px, contiguous)
    const int acg = at >> 4;        // channel group (4 ch), 0..7
    const float* Asrc = (t < 128) ? x : g;
    uint16_t* Adst    = (t < 128) ? u.a.Ax : u.a.Ag;
    size_t aoff[4];                 // + k0*4096 per iter
    #pragma unroll
    for (int i = 0; i < 4; ++i)
        aoff[i] = xbase + (size_t)(acg * 4 + i) * 4096 + apg * 4;
    // W: 1024 16B-chunks per matrix-chunk; thread does 4 (coalesced id = j*256+t)
    int woff[4], wlds[4];
    #pragma unroll
    for (int j = 0; j < 4; ++j) {
        const int id = j * 256 + t;
        const int o  = id >> 2;         // output row 0..255
        const int kq = id & 3;          // 16B quad within 32-k chunk
        woff[j] = o * 256 + kq * 8;     // + k0 per iter (elements)
        wlds[j] = o * STR + kq * 8;
    }

    float4 areg[4];
    uint4  wxr[4], wgr[4];

    // ---- prologue: issue loads for it=0 ----
    #pragma unroll
    for (int i = 0; i < 4; ++i) areg[i] = *(const float4*)&Asrc[aoff[i]];
    #pragma unroll
    for (int j = 0; j < 4; ++j) {
        wxr[j] = *(const uint4*)&Wxb[woff[j]];
        wgr[j] = *(const uint4*)&Wgb[woff[j]];
    }

    for (int it = 0; it < 8; ++it) {
        __syncthreads();   // previous iter's fragment reads complete

        // ---- store staged regs -> LDS (waits on the prefetched loads) ----
        #pragma unroll
        for (int p = 0; p < 4; ++p) {
            uint2 w;
            w.x = (uint32_t)f2b(areg[0][p]) | ((uint32_t)f2b(areg[1][p]) << 16);
            w.y = (uint32_t)f2b(areg[2][p]) | ((uint32_t)f2b(areg[3][p]) << 16);
            *(uint2*)&Adst[(apg * 4 + p) * STR + acg * 4] = w;
        }
        #pragma unroll
        for (int j = 0; j < 4; ++j) {
            *(uint4*)&WxS[wlds[j]] = wxr[j];
            *(uint4*)&WgS[wlds[j]] = wgr[j];
        }
        __syncthreads();

        // ---- prefetch next iter's tiles (in flight during MFMA phase) ----
        if (it < 7) {
            const int k1 = (it + 1) * 32;
            #pragma unroll
            for (int i = 0; i < 4; ++i)
                areg[i] = *(const float4*)&Asrc[aoff[i] + (size_t)k1 * 4096];
            #pragma unroll
            for (int j = 0; j < 4; ++j) {
                wxr[j] = *(const uint4*)&Wxb[woff[j] + k1];
                wgr[j] = *(const uint4*)&Wgb[woff[j] + k1];
            }
        }

        // ---- MFMA: D[m=pix][n=out], A[m=ln][k=q*8+j], B[n=ln][k=q*8+j] ----
        {
            bf16x8 af[4], bfr[4];
            #pragma unroll
            for (int mt = 0; mt < 4; ++mt)
                af[mt] = *(const bf16x8*)&u.a.Ax[(mt * 16 + ln) * STR + q * 8];
            #pragma unroll
            for (int nt = 0; nt < 4; ++nt)
                bfr[nt] = *(const bf16x8*)&WxS[(wv * 64 + nt * 16 + ln) * STR + q * 8];
            #pragma unroll
            for (int mt = 0; mt < 4; ++mt)
                #pragma unroll
                for (int nt = 0; nt < 4; ++nt)
                    acc[mt][nt] = __builtin_amdgcn_mfma_f32_16x16x32_bf16(af[mt], bfr[nt], acc[mt][nt], 0, 0, 0);

            #pragma unroll
            for (int mt = 0; mt < 4; ++mt)
                af[mt] = *(const bf16x8*)&u.a.Ag[(mt * 16 + ln) * STR + q * 8];
            #pragma unroll
            for (int nt = 0; nt < 4; ++nt)
                bfr[nt] = *(const bf16x8*)&WgS[(wv * 64 + nt * 16 + ln) * STR + q * 8];
            #pragma unroll
            for (int mt = 0; mt < 4; ++mt)
                #pragma unroll
                for (int nt = 0; nt < 4; ++nt)
                    acc[mt][nt] = __builtin_amdgcn_mfma_f32_16x16x32_bf16(af[mt], bfr[nt], acc[mt][nt], 0, 0, 0);
        }
    }

    __syncthreads();   // A LDS now reusable as epilogue scratch

    // ---- block-wide constants: sumA = sum(Wpsi*gamma), sumB = sum(Wpsi*beta) ----
    {
        float a  = Wpsi[t] * gamma[t];
        float bb = Wpsi[t] * beta[t];
        #pragma unroll
        for (int off = 32; off; off >>= 1) {
            a  += __shfl_xor(a, off, 64);
            bb += __shfl_xor(bb, off, 64);
        }
        if (lane == 0) { u.e.cpart[wv] = a; u.e.cpart[4 + wv] = bb; }
    }

    // per-lane channel constants (channel o = wv*64 + nt*16 + ln)
    float biasv[4], Ac[4];
    #pragma unroll
    for (int nt = 0; nt < 4; ++nt) {
        const int o = wv * 64 + nt * 16 + ln;
        biasv[nt] = bxg[o];
        Ac[nt]    = Wpsi[o] * gamma[o];
    }
    __syncthreads();
    const float sumA = u.e.cpart[0] + u.e.cpart[1] + u.e.cpart[2] + u.e.cpart[3];
    const float sumB = u.e.cpart[4] + u.e.cpart[5] + u.e.cpart[6] + u.e.cpart[7];

    // ---- per-pixel reductions: s, ss, t over this wave's 64 channels ----
    #pragma unroll
    for (int mt = 0; mt < 4; ++mt) {
        #pragma unroll
        for (int r = 0; r < 4; ++r) {
            float s = 0.f, ss = 0.f, tt = 0.f;
            #pragma unroll
            for (int nt = 0; nt < 4; ++nt) {
                float v = acc[mt][nt][r] + biasv[nt];
                v = fmaxf(v, 0.f);               // relu
                s += v; ss += v * v; tt += Ac[nt] * v;
            }
            #pragma unroll
            for (int off = 1; off < 16; off <<= 1) {   // reduce 16 lanes (n dim)
                s  += __shfl_xor(s,  off, 64);
                ss += __shfl_xor(ss, off, 64);
                tt += __shfl_xor(tt, off, 64);
            }
            if (ln == 0) {
                const int pix = mt * 16 + q * 4 + r;   // C/D row = q*4 + reg
                u.e.red[0][wv][pix] = s;
                u.e.red[1][wv][pix] = ss;
                u.e.red[2][wv][pix] = tt;
            }
        }
    }
    __syncthreads();

    // ---- LN + psi dot + sigmoid (one thread per pixel) ----
    if (t < 64) {
        const float s  = u.e.red[0][0][t] + u.e.red[0][1][t] + u.e.red[0][2][t] + u.e.red[0][3][t];
        const float ss = u.e.red[1][0][t] + u.e.red[1][1][t] + u.e.red[1][2][t] + u.e.red[1][3][t];
        const float tt = u.e.red[2][0][t] + u.e.red[2][1][t] + u.e.red[2][2][t] + u.e.red[2][3][t];
        const float mu   = s * (1.f / 256.f);
        const float var  = ss * (1.f / 256.f) - mu * mu;
        const float rstd = rsqrtf(var + LN_EPS);
        const float z    = rstd * (tt - mu * sumA) + sumB + bpsi[0];
        u.e.psi[t] = 1.f / (1.f + __expf(-z));
    }
    __syncthreads();

    // ---- out[c][p] = psi[p] * x[c][p], 16 channels x 4 pixels per thread ----
    const int pc = (t & 15) * 4;
    const float p0 = u.e.psi[pc], p1 = u.e.psi[pc + 1], p2 = u.e.psi[pc + 2], p3 = u.e.psi[pc + 3];
    const int crow = t >> 4;
    #pragma unroll
    for (int pass = 0; pass < 16; ++pass) {
        const int c = pass * 16 + crow;
        const size_t off = xbase + (size_t)c * 4096 + pc;
        const float4 d = *(const float4*)&x[off];
        float4 o;
        o.x = d.x * p0; o.y = d.y * p1; o.z = d.z * p2; o.w = d.w * p3;
        *(float4*)&out[off] = o;
    }
}

extern "C" void kernel_launch(void* const* d_in, const int* in_sizes, int n_in,
                              void* d_out, int out_size, void* d_ws, size_t ws_size,
                              hipStream_t stream) {
    const float* x    = (const float*)d_in[0];
    const float* g    = (const float*)d_in[1];
    const float* Wx   = (const float*)d_in[2];
    const float* Wg   = (const float*)d_in[3];
    const float* Wpsi = (const float*)d_in[4];
    const float* gam  = (const float*)d_in[5];
    const float* bet  = (const float*)d_in[6];
    const float* bxg  = (const float*)d_in[7];
    const float* bpsi = (const float*)d_in[8];
    float* out        = (float*)d_out;

    uint16_t* Wxb = (uint16_t*)d_ws;                 // 131072 B
    uint16_t* Wgb = (uint16_t*)((char*)d_ws + 131072);

    wconv_kernel<<<dim3(64), dim3(256), 0, stream>>>(
        (const float4*)Wx, (const float4*)Wg, (uint2*)Wxb, (uint2*)Wgb);
    attgate_kernel<<<dim3(1024), dim3(256), 0, stream>>>(
        x, g, Wxb, Wgb, Wpsi, gam, bet, bxg, bpsi, out);
}

// Round 4
// 205.575 us; speedup vs baseline: 1.5370x; 1.5370x over previous
//
#include <hip/hip_runtime.h>
#include <stdint.h>

// AttentionGate fused kernel, MI355X gfx950. Inputs fp32 (confirmed R2).
//
// Prepass: Wx, Wg fp32 -> bf16 in FRAGMENT-CHUNK layout [it][n][32k] so the
// main kernel reads B-operand MFMA fragments directly from global (L2-hot,
// fully coalesced) — no W staging in LDS, no W barrier traffic.
// Main kernel, per block: 64 px x 256 out. A (x,g) tiles double-buffered in
// LDS (bf16, transposed to [px][k]); ONE barrier per K-iter; A prefetch for
// it+1 held in 16 scalar VGPRs (no spill; first use after the MFMA phase).
// A staging is conflict-free: thread = 1 px x 16 ch, ds_write_b128.
// Epilogue: bias+relu in regs; LN + psi fused to 3 per-pixel reductions
// (s, ss, t) -> sigmoid -> out = psi * x (x re-read, L3-warm).

typedef __bf16 bf16x8 __attribute__((ext_vector_type(8)));
typedef float f32x4 __attribute__((ext_vector_type(4)));

#define STR 40            // LDS row stride in shorts (80 B; rows 0-7 tile all banks)
#define LN_EPS 1e-5f

__device__ __forceinline__ uint16_t f2b(float f) {
    union { float f; uint32_t i; } v; v.f = f;
    uint32_t x = v.i;
    return (uint16_t)((x + 0x7FFFu + ((x >> 16) & 1u)) >> 16);  // RNE
}

struct EpiShared {
    float red[3][4][64];   // s, ss, t partials: [value][wave][pixel]
    float psi[64];
    float cpart[8];        // per-wave partials: sumA (0..3), sumB (4..7)
};

union ALds {
    uint16_t a[2][2][64 * STR];   // [buf][tensor: 0=x 1=g][row*STR + ch]  20 KiB
    EpiShared e;
};

// ---- prepass: W fp32 -> bf16 chunk layout: dst[it*8192 + n*32 + kk] = W[n][it*32+kk]
__global__ void wconv_kernel(const float* __restrict__ Wx, const float* __restrict__ Wg,
                             uint16_t* __restrict__ ox, uint16_t* __restrict__ og) {
    const int i  = blockIdx.x * 256 + threadIdx.x;   // 64 blocks -> 16384
    const int n  = i >> 6;
    const int k4 = (i & 63) * 4;
    const int it = k4 >> 5;
    const int kk = k4 & 31;
    const int dst = it * 8192 + n * 32 + kk;
    const float4 a = *(const float4*)&Wx[n * 256 + k4];
    const float4 b = *(const float4*)&Wg[n * 256 + k4];
    uint2 pa, pb;
    pa.x = (uint32_t)f2b(a.x) | ((uint32_t)f2b(a.y) << 16);
    pa.y = (uint32_t)f2b(a.z) | ((uint32_t)f2b(a.w) << 16);
    pb.x = (uint32_t)f2b(b.x) | ((uint32_t)f2b(b.y) << 16);
    pb.y = (uint32_t)f2b(b.z) | ((uint32_t)f2b(b.w) << 16);
    *(uint2*)&ox[dst] = pa;
    *(uint2*)&og[dst] = pb;
}

__device__ __forceinline__ void stage_load(float av[16], const float* __restrict__ Asrc,
                                           size_t abase, int c0, int px) {
    #pragma unroll
    for (int j = 0; j < 2; ++j)
        #pragma unroll
        for (int c = 0; c < 8; ++c)
            av[j * 8 + c] = Asrc[abase + (size_t)(c0 + j * 16 + c) * 4096 + px];
}

__device__ __forceinline__ void stage_store(const float av[16], uint16_t* dstrow, int c0) {
    #pragma unroll
    for (int j = 0; j < 2; ++j) {
        uint4 w;
        w.x = (uint32_t)f2b(av[j*8+0]) | ((uint32_t)f2b(av[j*8+1]) << 16);
        w.y = (uint32_t)f2b(av[j*8+2]) | ((uint32_t)f2b(av[j*8+3]) << 16);
        w.z = (uint32_t)f2b(av[j*8+4]) | ((uint32_t)f2b(av[j*8+5]) << 16);
        w.w = (uint32_t)f2b(av[j*8+6]) | ((uint32_t)f2b(av[j*8+7]) << 16);
        *(uint4*)&dstrow[c0 + j * 16] = w;   // ds_write_b128, conflict-free
    }
}

__global__ __launch_bounds__(256, 3) void attgate_kernel(
    const float* __restrict__ x,
    const float* __restrict__ g,
    const uint16_t* __restrict__ Wxb,   // bf16 chunk layout [8][256][32]
    const uint16_t* __restrict__ Wgb,
    const float* __restrict__ Wpsi,
    const float* __restrict__ gamma,
    const float* __restrict__ beta,
    const float* __restrict__ bxg,
    const float* __restrict__ bpsi,
    float* __restrict__ out)
{
    __shared__ __align__(16) ALds u;

    const int t    = threadIdx.x;
    const int lane = t & 63;
    const int wv   = t >> 6;        // wave 0..3 -> output-channel slice
    const int ln   = lane & 15;     // tile row/col index
    const int q    = lane >> 4;     // quad 0..3 (k-quad)

    const int gp0  = blockIdx.x * 64;            // global pixel base
    const int b    = gp0 >> 12;                  // batch (4096 px per image)
    const int pix0 = gp0 & 4095;
    const size_t xbase = (size_t)b * (256 * 4096) + pix0;  // + c*4096 + p

    f32x4 acc[4][4];
    #pragma unroll
    for (int i = 0; i < 4; ++i)
        #pragma unroll
        for (int j = 0; j < 4; ++j)
            acc[i][j] = (f32x4){0.f, 0.f, 0.f, 0.f};

    // ---- A staging mapping: thread = 1 pixel x 16 channels (of this iter's 32)
    const int at  = t & 127;
    const int px  = at & 63;
    const int cg  = at >> 6;        // 0/1
    const int c0  = cg * 8;         // ch cols c0..c0+7 and c0+16..c0+23
    const float* Asrc = (t < 128) ? x : g;
    const int tens    = (t < 128) ? 0 : 1;

    float av[16];
    stage_load(av, Asrc, xbase, c0, px);                 // it = 0
    stage_store(av, &u.a[0][tens][px * STR], c0);

    const int fro = wv * 64 + ln;   // W fragment row base offset

    for (int it = 0; it < 8; ++it) {
        __syncthreads();            // buf[it&1] ready; prior reads drained
        const int cur = it & 1;
        const uint16_t* Wxi = Wxb + it * 8192;
        const uint16_t* Wgi = Wgb + it * 8192;

        // B fragments for Wx (global, L2-hot, coalesced 1 KiB/wave/nt)
        bf16x8 bx[4];
        #pragma unroll
        for (int nt = 0; nt < 4; ++nt)
            bx[nt] = *(const bf16x8*)&Wxi[(fro + nt * 16) * 32 + q * 8];

        // prefetch A for it+1 (16 dwords; first use after MFMA phase)
        if (it < 7)
            stage_load(av, Asrc, xbase + (size_t)((it + 1) * 32) * 4096, c0, px);

        // A fragments (x) from LDS + MFMA x
        bf16x8 af[4];
        #pragma unroll
        for (int mt = 0; mt < 4; ++mt)
            af[mt] = *(const bf16x8*)&u.a[cur][0][(mt * 16 + ln) * STR + q * 8];
        #pragma unroll
        for (int mt = 0; mt < 4; ++mt)
            #pragma unroll
            for (int nt = 0; nt < 4; ++nt)
                acc[mt][nt] = __builtin_amdgcn_mfma_f32_16x16x32_bf16(af[mt], bx[nt], acc[mt][nt], 0, 0, 0);

        // B fragments for Wg + A fragments (g) + MFMA g
        bf16x8 bg[4];
        #pragma unroll
        for (int nt = 0; nt < 4; ++nt)
            bg[nt] = *(const bf16x8*)&Wgi[(fro + nt * 16) * 32 + q * 8];
        #pragma unroll
        for (int mt = 0; mt < 4; ++mt)
            af[mt] = *(const bf16x8*)&u.a[cur][1][(mt * 16 + ln) * STR + q * 8];
        #pragma unroll
        for (int mt = 0; mt < 4; ++mt)
            #pragma unroll
            for (int nt = 0; nt < 4; ++nt)
                acc[mt][nt] = __builtin_amdgcn_mfma_f32_16x16x32_bf16(af[mt], bg[nt], acc[mt][nt], 0, 0, 0);

        // store prefetched A -> other buffer (waits on the it+1 loads here)
        if (it < 7)
            stage_store(av, &u.a[cur ^ 1][tens][px * STR], c0);
    }

    __syncthreads();   // A LDS now reusable as epilogue scratch

    // ---- block-wide constants: sumA = sum(Wpsi*gamma), sumB = sum(Wpsi*beta) ----
    {
        float a  = Wpsi[t] * gamma[t];
        float bb = Wpsi[t] * beta[t];
        #pragma unroll
        for (int off = 32; off; off >>= 1) {
            a  += __shfl_xor(a, off, 64);
            bb += __shfl_xor(bb, off, 64);
        }
        if (lane == 0) { u.e.cpart[wv] = a; u.e.cpart[4 + wv] = bb; }
    }

    // per-lane channel constants (channel o = wv*64 + nt*16 + ln)
    float biasv[4], Ac[4];
    #pragma unroll
    for (int nt = 0; nt < 4; ++nt) {
        const int o = wv * 64 + nt * 16 + ln;
        biasv[nt] = bxg[o];
        Ac[nt]    = Wpsi[o] * gamma[o];
    }
    __syncthreads();
    const float sumA = u.e.cpart[0] + u.e.cpart[1] + u.e.cpart[2] + u.e.cpart[3];
    const float sumB = u.e.cpart[4] + u.e.cpart[5] + u.e.cpart[6] + u.e.cpart[7];

    // ---- per-pixel reductions: s, ss, t over this wave's 64 channels ----
    #pragma unroll
    for (int mt = 0; mt < 4; ++mt) {
        #pragma unroll
        for (int r = 0; r < 4; ++r) {
            float s = 0.f, ss = 0.f, tt = 0.f;
            #pragma unroll
            for (int nt = 0; nt < 4; ++nt) {
                float v = acc[mt][nt][r] + biasv[nt];
                v = fmaxf(v, 0.f);               // relu
                s += v; ss += v * v; tt += Ac[nt] * v;
            }
            #pragma unroll
            for (int off = 1; off < 16; off <<= 1) {   // reduce 16 lanes (n dim)
                s  += __shfl_xor(s,  off, 64);
                ss += __shfl_xor(ss, off, 64);
                tt += __shfl_xor(tt, off, 64);
            }
            if (ln == 0) {
                const int pix = mt * 16 + q * 4 + r;   // C/D row = q*4 + reg
                u.e.red[0][wv][pix] = s;
                u.e.red[1][wv][pix] = ss;
                u.e.red[2][wv][pix] = tt;
            }
        }
    }
    __syncthreads();

    // ---- LN + psi dot + sigmoid (one thread per pixel) ----
    if (t < 64) {
        const float s  = u.e.red[0][0][t] + u.e.red[0][1][t] + u.e.red[0][2][t] + u.e.red[0][3][t];
        const float ss = u.e.red[1][0][t] + u.e.red[1][1][t] + u.e.red[1][2][t] + u.e.red[1][3][t];
        const float tt = u.e.red[2][0][t] + u.e.red[2][1][t] + u.e.red[2][2][t] + u.e.red[2][3][t];
        const float mu   = s * (1.f / 256.f);
        const float var  = ss * (1.f / 256.f) - mu * mu;
        const float rstd = rsqrtf(var + LN_EPS);
        const float z    = rstd * (tt - mu * sumA) + sumB + bpsi[0];
        u.e.psi[t] = 1.f / (1.f + __expf(-z));
    }
    __syncthreads();

    // ---- out[c][p] = psi[p] * x[c][p], 16 channels x 4 pixels per thread ----
    const int pc = (t & 15) * 4;
    const float p0 = u.e.psi[pc], p1 = u.e.psi[pc + 1], p2 = u.e.psi[pc + 2], p3 = u.e.psi[pc + 3];
    const int crow = t >> 4;
    #pragma unroll
    for (int pass = 0; pass < 16; ++pass) {
        const int c = pass * 16 + crow;
        const size_t off = xbase + (size_t)c * 4096 + pc;
        const float4 d = *(const float4*)&x[off];
        float4 o;
        o.x = d.x * p0; o.y = d.y * p1; o.z = d.z * p2; o.w = d.w * p3;
        *(float4*)&out[off] = o;
    }
}

extern "C" void kernel_launch(void* const* d_in, const int* in_sizes, int n_in,
                              void* d_out, int out_size, void* d_ws, size_t ws_size,
                              hipStream_t stream) {
    const float* x    = (const float*)d_in[0];
    const float* g    = (const float*)d_in[1];
    const float* Wx   = (const float*)d_in[2];
    const float* Wg   = (const float*)d_in[3];
    const float* Wpsi = (const float*)d_in[4];
    const float* gam  = (const float*)d_in[5];
    const float* bet  = (const float*)d_in[6];
    const float* bxg  = (const float*)d_in[7];
    const float* bpsi = (const float*)d_in[8];
    float* out        = (float*)d_out;

    uint16_t* Wxb = (uint16_t*)d_ws;                 // 131072 B
    uint16_t* Wgb = (uint16_t*)((char*)d_ws + 131072);

    wconv_kernel<<<dim3(64), dim3(256), 0, stream>>>(Wx, Wg, Wxb, Wgb);
    attgate_kernel<<<dim3(1024), dim3(256), 0, stream>>>(
        x, g, Wxb, Wgb, Wpsi, gam, bet, bxg, bpsi, out);
}